// Round 1
// baseline (689.149 us; speedup 1.0000x reference)
//
#include <hip/hip_runtime.h>

#define NCOLS 4096
#define QMAXF 127.0f
#define EPSF 1e-5f

__global__ __launch_bounds__(256) void fused_addrms_dualquant(
    const float* __restrict__ x1,
    const float* __restrict__ x2,
    const float* __restrict__ gamma,
    const float* __restrict__ sm1,
    const float* __restrict__ sm2,
    float* __restrict__ o_xsum,
    float* __restrict__ o_ynorm,
    float* __restrict__ o_y1,
    float* __restrict__ o_s1,
    float* __restrict__ o_y2,
    float* __restrict__ o_s2)
{
    const int row = blockIdx.x;
    const long long base = (long long)row * NCOLS;
    const int t = threadIdx.x;

    // ---- pass 1: load, residual add, write x_sum, accumulate sum of squares ----
    float4 s[4];
    float ssq = 0.f;
#pragma unroll
    for (int c = 0; c < 4; ++c) {
        const int idx = c * 1024 + t * 4;
        float4 a = *(const float4*)(x1 + base + idx);
        float4 b = *(const float4*)(x2 + base + idx);
        float4 v;
        v.x = a.x + b.x; v.y = a.y + b.y; v.z = a.z + b.z; v.w = a.w + b.w;
        s[c] = v;
        ssq += v.x * v.x + v.y * v.y + v.z * v.z + v.w * v.w;
        *(float4*)(o_xsum + base + idx) = v;
    }

    // ---- block reduction of ssq (wave64 shuffle, then LDS across 4 waves) ----
#pragma unroll
    for (int off = 32; off > 0; off >>= 1) ssq += __shfl_down(ssq, off);

    __shared__ float red[4];
    __shared__ float s_invrms;
    if ((t & 63) == 0) red[t >> 6] = ssq;
    __syncthreads();
    if (t == 0) {
        float tot = red[0] + red[1] + red[2] + red[3];
        s_invrms = rsqrtf(tot * (1.0f / (float)NCOLS) + EPSF);
    }
    __syncthreads();
    const float inv_rms = s_invrms;

    // ---- pass 2: y_norm, smoothed values, per-row amax ----
    float4 ys1[4], ys2[4];
    float a1 = 0.f, a2 = 0.f;
#pragma unroll
    for (int c = 0; c < 4; ++c) {
        const int idx = c * 1024 + t * 4;
        float4 g  = *(const float4*)(gamma + idx);
        float4 m1 = *(const float4*)(sm1 + idx);
        float4 m2 = *(const float4*)(sm2 + idx);
        float4 y;
        y.x = s[c].x * inv_rms * g.x;
        y.y = s[c].y * inv_rms * g.y;
        y.z = s[c].z * inv_rms * g.z;
        y.w = s[c].w * inv_rms * g.w;
        *(float4*)(o_ynorm + base + idx) = y;
        ys1[c].x = y.x * m1.x; ys1[c].y = y.y * m1.y;
        ys1[c].z = y.z * m1.z; ys1[c].w = y.w * m1.w;
        ys2[c].x = y.x * m2.x; ys2[c].y = y.y * m2.y;
        ys2[c].z = y.z * m2.z; ys2[c].w = y.w * m2.w;
        a1 = fmaxf(a1, fmaxf(fmaxf(fabsf(ys1[c].x), fabsf(ys1[c].y)),
                             fmaxf(fabsf(ys1[c].z), fabsf(ys1[c].w))));
        a2 = fmaxf(a2, fmaxf(fmaxf(fabsf(ys2[c].x), fabsf(ys2[c].y)),
                             fmaxf(fabsf(ys2[c].z), fabsf(ys2[c].w))));
    }

    // ---- block max reductions ----
#pragma unroll
    for (int off = 32; off > 0; off >>= 1) {
        a1 = fmaxf(a1, __shfl_down(a1, off));
        a2 = fmaxf(a2, __shfl_down(a2, off));
    }
    __shared__ float redm1[4], redm2[4];
    __shared__ float s_sc1, s_sc2;
    if ((t & 63) == 0) { redm1[t >> 6] = a1; redm2[t >> 6] = a2; }
    __syncthreads();
    if (t == 0) {
        float m1v = fmaxf(fmaxf(redm1[0], redm1[1]), fmaxf(redm1[2], redm1[3]));
        float m2v = fmaxf(fmaxf(redm2[0], redm2[1]), fmaxf(redm2[2], redm2[3]));
        float sc1 = m1v / QMAXF;
        float sc2 = m2v / QMAXF;
        o_s1[row] = sc1;
        o_s2[row] = sc2;
        s_sc1 = sc1;
        s_sc2 = sc2;
    }
    __syncthreads();
    const float sc1 = s_sc1, sc2 = s_sc2;

    // ---- pass 3: quantize (IEEE div + rintf to match np.round half-even) ----
#pragma unroll
    for (int c = 0; c < 4; ++c) {
        const int idx = c * 1024 + t * 4;
        float4 q1, q2;
        q1.x = fminf(fmaxf(rintf(ys1[c].x / sc1), -128.f), 127.f);
        q1.y = fminf(fmaxf(rintf(ys1[c].y / sc1), -128.f), 127.f);
        q1.z = fminf(fmaxf(rintf(ys1[c].z / sc1), -128.f), 127.f);
        q1.w = fminf(fmaxf(rintf(ys1[c].w / sc1), -128.f), 127.f);
        q2.x = fminf(fmaxf(rintf(ys2[c].x / sc2), -128.f), 127.f);
        q2.y = fminf(fmaxf(rintf(ys2[c].y / sc2), -128.f), 127.f);
        q2.z = fminf(fmaxf(rintf(ys2[c].z / sc2), -128.f), 127.f);
        q2.w = fminf(fmaxf(rintf(ys2[c].w / sc2), -128.f), 127.f);
        *(float4*)(o_y1 + base + idx) = q1;
        *(float4*)(o_y2 + base + idx) = q2;
    }
}

extern "C" void kernel_launch(void* const* d_in, const int* in_sizes, int n_in,
                              void* d_out, int out_size, void* d_ws, size_t ws_size,
                              hipStream_t stream) {
    const float* x1    = (const float*)d_in[0];
    const float* x2    = (const float*)d_in[1];
    const float* gamma = (const float*)d_in[2];
    const float* sm1   = (const float*)d_in[3];
    const float* sm2   = (const float*)d_in[4];

    const long long n_elem = in_sizes[0];        // B*S*N
    const int ncols = in_sizes[2];               // N = 4096
    const long long rows = n_elem / ncols;       // B*S = 8192

    float* out = (float*)d_out;
    float* o_xsum  = out;
    float* o_ynorm = out + n_elem;
    float* o_y1    = out + 2 * n_elem;
    float* o_s1    = out + 3 * n_elem;
    float* o_y2    = o_s1 + rows;
    float* o_s2    = o_y2 + n_elem;

    fused_addrms_dualquant<<<dim3((unsigned)rows), dim3(256), 0, stream>>>(
        x1, x2, gamma, sm1, sm2, o_xsum, o_ynorm, o_y1, o_s1, o_y2, o_s2);
}